// Round 9
// baseline (190.425 us; speedup 1.0000x reference)
//
#include <hip/hip_runtime.h>
#include <math.h>

#define B_   8
#define C_   64
#define CK_  8
#define L_   4096

typedef __attribute__((ext_vector_type(8))) __bf16 bf16x8;
typedef __attribute__((ext_vector_type(4))) __bf16 bf16x4;
typedef __attribute__((ext_vector_type(4))) float  f32x4;

// ---------------- Kernel 1: QKV projection -> bf16 ----------------
// (byte-identical to the r8 hardware-verified version)
__global__ __launch_bounds__(256) void qkv_kernel(
    const float* __restrict__ x,
    const float* __restrict__ Wq, const float* __restrict__ bq,
    const float* __restrict__ Wk, const float* __restrict__ bk,
    const float* __restrict__ Wv, const float* __restrict__ bv,
    __bf16* __restrict__ qo, __bf16* __restrict__ ko, __bf16* __restrict__ vpack)
{
    __shared__ float LWq[CK_ * C_];
    __shared__ float LWk[CK_ * C_];
    __shared__ float LWv[C_ * C_];      // row-major [c_out][c_in]
    __shared__ __bf16 Lqs[64 * 8];
    __shared__ __bf16 Lks[64 * 8];

    const int tid = threadIdx.x;
    if (tid < 128) {
        ((float4*)LWq)[tid] = ((const float4*)Wq)[tid];
        ((float4*)LWk)[tid] = ((const float4*)Wk)[tid];
    }
    #pragma unroll
    for (int j = 0; j < 4; ++j)
        ((float4*)LWv)[tid + j * 256] = ((const float4*)Wv)[tid + j * 256];
    __syncthreads();

    const int b  = blockIdx.x >> 6;
    const int t  = blockIdx.x & 63;
    const int l0 = t << 6;
    const int lg = tid & 15;
    const int g  = tid >> 4;

    float va[4][4];
    float qk[4];
    #pragma unroll
    for (int j = 0; j < 4; ++j) {
        float bb = bv[4 * g + j];
        va[j][0] = bb; va[j][1] = bb; va[j][2] = bb; va[j][3] = bb;
    }
    {
        float bb = (g < 8) ? bq[g] : bk[g - 8];
        qk[0] = bb; qk[1] = bb; qk[2] = bb; qk[3] = bb;
    }
    const float* wqk = (g < 8) ? (LWq + g * C_) : (LWk + (g - 8) * C_);

    const float* xp = x + ((size_t)b * C_) * L_ + l0 + lg * 4;
    #pragma unroll 4
    for (int c4 = 0; c4 < 16; ++c4) {
        float4 xv[4];
        #pragma unroll
        for (int u = 0; u < 4; ++u)
            xv[u] = *(const float4*)(xp + (size_t)(4 * c4 + u) * L_);
        #pragma unroll
        for (int j = 0; j < 4; ++j) {
            float4 wv = ((const float4*)(LWv + (4 * g + j) * C_))[c4];
            float* a = va[j];
            a[0]=fmaf(wv.x,xv[0].x,a[0]); a[1]=fmaf(wv.x,xv[0].y,a[1]); a[2]=fmaf(wv.x,xv[0].z,a[2]); a[3]=fmaf(wv.x,xv[0].w,a[3]);
            a[0]=fmaf(wv.y,xv[1].x,a[0]); a[1]=fmaf(wv.y,xv[1].y,a[1]); a[2]=fmaf(wv.y,xv[1].z,a[2]); a[3]=fmaf(wv.y,xv[1].w,a[3]);
            a[0]=fmaf(wv.z,xv[2].x,a[0]); a[1]=fmaf(wv.z,xv[2].y,a[1]); a[2]=fmaf(wv.z,xv[2].z,a[2]); a[3]=fmaf(wv.z,xv[2].w,a[3]);
            a[0]=fmaf(wv.w,xv[3].x,a[0]); a[1]=fmaf(wv.w,xv[3].y,a[1]); a[2]=fmaf(wv.w,xv[3].z,a[2]); a[3]=fmaf(wv.w,xv[3].w,a[3]);
        }
        {
            float4 wv = ((const float4*)wqk)[c4];
            qk[0]=fmaf(wv.x,xv[0].x,qk[0]); qk[1]=fmaf(wv.x,xv[0].y,qk[1]); qk[2]=fmaf(wv.x,xv[0].z,qk[2]); qk[3]=fmaf(wv.x,xv[0].w,qk[3]);
            qk[0]=fmaf(wv.y,xv[1].x,qk[0]); qk[1]=fmaf(wv.y,xv[1].y,qk[1]); qk[2]=fmaf(wv.y,xv[1].z,qk[2]); qk[3]=fmaf(wv.y,xv[1].w,qk[3]);
            qk[0]=fmaf(wv.z,xv[2].x,qk[0]); qk[1]=fmaf(wv.z,xv[2].y,qk[1]); qk[2]=fmaf(wv.z,xv[2].z,qk[2]); qk[3]=fmaf(wv.z,xv[2].w,qk[3]);
            qk[0]=fmaf(wv.w,xv[3].x,qk[0]); qk[1]=fmaf(wv.w,xv[3].y,qk[1]); qk[2]=fmaf(wv.w,xv[3].z,qk[2]); qk[3]=fmaf(wv.w,xv[3].w,qk[3]);
        }
    }

    // vpack stores: thread (g,lg) holds c=4g+j, l=l0+4lg+u.
    {
        __bf16* vt = vpack + ((size_t)b * 64 + t) * 4096;
        const int cb = g >> 2;
        const int sg = lg >> 2;
        const int qd = lg & 3;
        #pragma unroll
        for (int j = 0; j < 4; ++j) {
            bf16x4 vv;
            vv[0]=(__bf16)va[j][0]; vv[1]=(__bf16)va[j][1]; vv[2]=(__bf16)va[j][2]; vv[3]=(__bf16)va[j][3];
            *(bf16x4*)(vt + ((size_t)((cb * 4 + sg) * 64 + qd * 16 + (g & 3) * 4 + j)) * 4) = vv;
        }
    }
    // q/k: gather through LDS, then b128 stores
    #pragma unroll
    for (int u = 0; u < 4; ++u) {
        if (g < 8) Lqs[(lg * 4 + u) * 8 + g]       = (__bf16)qk[u];
        else       Lks[(lg * 4 + u) * 8 + (g - 8)] = (__bf16)qk[u];
    }
    __syncthreads();
    if (tid < 64) {
        *(bf16x8*)(qo + ((size_t)b * L_ + l0 + tid) * 8) = *(bf16x8*)(Lqs + tid * 8);
        *(bf16x8*)(ko + ((size_t)b * L_ + l0 + tid) * 8) = *(bf16x8*)(Lks + tid * 8);
    }
}

// ---------------- Kernel 2: fused attention ------------------------------
// grid: B*64 (b,mb) x 512 thr (8 waves: lh=w>>1 l-quarter, wh=w&1 m-half).
// Each wave owns 32 m (kf0/kf1 -> acc0/acc1) over its l-quarter (16 tiles,
// 8 pair-iterations). V tile read by only 2 waves (was 4) -> LDS read volume
// halved; one V a8 fragment feeds BOTH m-halves. Single-buffered LDS: loads
// for iter i+1 issued at compute(i) start (reg-staged), bar1 (reads done),
// ds_write, bar2. Read pattern/pairing byte-equivalent to r8 (verified).
// Epilogue: 4-way lh reduce via 48KB Sc overlay on Lv, normalize, +x.
__global__ __launch_bounds__(512, 4) void attn_kernel(
    const __bf16* __restrict__ q, const __bf16* __restrict__ kT,
    const __bf16* __restrict__ VP, const float* __restrict__ x,
    const float* __restrict__ gamma_p, float* __restrict__ out)
{
    __shared__ __bf16 Lv[4][2][4096];   // 64 KB: [quarter][pair-half][tile]
    __shared__ float  csA[16][16];

    const int tid  = threadIdx.x;
    const int w    = tid >> 6;
    const int lane = tid & 63;
    const int quad = lane >> 4;
    const int l16  = lane & 15;
    const int wh   = w & 1;
    const int lh   = w >> 1;
    const int mb   = blockIdx.x & 63;
    const int b    = blockIdx.x >> 6;
    const int m0   = mb << 6;

    const __bf16* vp = VP + (size_t)b * (64 * 4096);
    const __bf16* qb = q  + (size_t)b * L_ * CK_;

    bf16x8 kf0 = {}, kf1 = {};
    if (quad == 0) {
        kf0 = *(const bf16x8*)(kT + ((size_t)b * L_ + m0 + wh * 32 + l16) * CK_);
        kf1 = *(const bf16x8*)(kT + ((size_t)b * L_ + m0 + wh * 32 + 16 + l16) * CK_);
    }

    // staging: wave w owns LDS slot Lv[lh][wh], fed from tile lh*16 + 2i + wh
    const __bf16* gs = vp + ((size_t)(lh * 16 + wh)) * 4096 + lane * 8;
    __bf16* Ld = &Lv[lh][wh][0] + lane * 8;

    f32x4 acc0[4] = {}, acc1[4] = {};
    float csum0 = 0.f, csum1 = 0.f;
    bf16x8 r[8];

    // prologue: stage pair 0 (tiles lh*16 + {0,1})
    #pragma unroll
    for (int k = 0; k < 8; ++k) r[k] = *(const bf16x8*)(gs + k * 512);
    #pragma unroll
    for (int k = 0; k < 8; ++k) *(bf16x8*)(Ld + k * 512) = r[k];
    __syncthreads();

    for (int i = 0; i < 8; ++i) {
        if (i < 7) {    // issue next-pair loads early; land under compute
            #pragma unroll
            for (int k = 0; k < 8; ++k)
                r[k] = *(const bf16x8*)(gs + (size_t)(2 * (i + 1)) * 4096 + k * 512);
        }

        const int te = lh * 16 + 2 * i;     // even tile of this quarter's pair
        bf16x8 qA[4], qB[4];
        #pragma unroll
        for (int sg = 0; sg < 4; ++sg) {
            qA[sg] = *(const bf16x8*)(qb + (size_t)(te * 64 + sg * 16 + l16) * CK_);
            qB[sg] = *(const bf16x8*)(qb + (size_t)((te + 1) * 64 + sg * 16 + l16) * CK_);
        }

        const __bf16* LbA = &Lv[lh][0][0];
        const __bf16* LbB = &Lv[lh][1][0];
        #pragma unroll
        for (int sg = 0; sg < 4; ++sg) {
            f32x4 svA0 = __builtin_amdgcn_mfma_f32_16x16x32_bf16(qA[sg], kf0, (f32x4){0.f,0.f,0.f,0.f}, 0, 0, 0);
            f32x4 svB0 = __builtin_amdgcn_mfma_f32_16x16x32_bf16(qB[sg], kf0, (f32x4){0.f,0.f,0.f,0.f}, 0, 0, 0);
            f32x4 svA1 = __builtin_amdgcn_mfma_f32_16x16x32_bf16(qA[sg], kf1, (f32x4){0.f,0.f,0.f,0.f}, 0, 0, 0);
            f32x4 svB1 = __builtin_amdgcn_mfma_f32_16x16x32_bf16(qB[sg], kf1, (f32x4){0.f,0.f,0.f,0.f}, 0, 0, 0);

            bf16x4 pA0, pB0, pA1, pB1;
            #pragma unroll
            for (int r2 = 0; r2 < 4; ++r2) {
                const float eA0 = __expf(svA0[r2]);
                const float eB0 = __expf(svB0[r2]);
                const float eA1 = __expf(svA1[r2]);
                const float eB1 = __expf(svB1[r2]);
                csum0 += eA0 + eB0;
                csum1 += eA1 + eB1;
                pA0[r2] = (__bf16)eA0; pB0[r2] = (__bf16)eB0;
                pA1[r2] = (__bf16)eA1; pB1[r2] = (__bf16)eB1;
            }
            bf16x8 p80 = __builtin_shufflevector(pA0, pB0, 0, 1, 2, 3, 4, 5, 6, 7);
            bf16x8 p81 = __builtin_shufflevector(pA1, pB1, 0, 1, 2, 3, 4, 5, 6, 7);

            #pragma unroll
            for (int cb = 0; cb < 4; ++cb) {
                bf16x4 vfA = *(const bf16x4*)(LbA + ((size_t)((cb * 4 + sg) * 64 + lane)) * 4);
                bf16x4 vfB = *(const bf16x4*)(LbB + ((size_t)((cb * 4 + sg) * 64 + lane)) * 4);
                bf16x8 a8 = __builtin_shufflevector(vfA, vfB, 0, 1, 2, 3, 4, 5, 6, 7);
                acc0[cb] = __builtin_amdgcn_mfma_f32_16x16x32_bf16(a8, p80, acc0[cb], 0, 0, 0);
                acc1[cb] = __builtin_amdgcn_mfma_f32_16x16x32_bf16(a8, p81, acc1[cb], 0, 0, 0);
            }
        }

        if (i < 7) {
            __syncthreads();    // all reads of Lv for iter i done
            #pragma unroll
            for (int k = 0; k < 8; ++k) *(bf16x8*)(Ld + k * 512) = r[k];
            __syncthreads();    // writes published
        }
    }

    // ---- epilogue: 4-way lh reduce, normalize, residual ----
    __syncthreads();            // all V reads done; Lv reusable as Sc
    float* Sc = (float*)&Lv[0][0][0];   // 48 KB used: Sc[3][4096]
    if (lh >= 1) {
        float* S = Sc + (size_t)(lh - 1) * 4096;
        #pragma unroll
        for (int cb = 0; cb < 4; ++cb) {
            #pragma unroll
            for (int r2 = 0; r2 < 4; ++r2) {
                const int c = cb * 16 + quad * 4 + r2;
                S[c * 64 + wh * 32 + l16]      = acc0[cb][r2];
                S[c * 64 + wh * 32 + 16 + l16] = acc1[cb][r2];
            }
        }
    }
    csum0 += __shfl_xor(csum0, 16);
    csum0 += __shfl_xor(csum0, 32);
    csum1 += __shfl_xor(csum1, 16);
    csum1 += __shfl_xor(csum1, 32);
    if (quad == 0) {
        csA[lh * 4 + wh * 2 + 0][l16] = csum0;
        csA[lh * 4 + wh * 2 + 1][l16] = csum1;
    }
    __syncthreads();

    if (lh == 0) {
        const float g0 = gamma_p[0];
        const float rinv0 = g0 / (csA[wh * 2 + 0][l16] + csA[4 + wh * 2 + 0][l16]
                                + csA[8 + wh * 2 + 0][l16] + csA[12 + wh * 2 + 0][l16]);
        const float rinv1 = g0 / (csA[wh * 2 + 1][l16] + csA[4 + wh * 2 + 1][l16]
                                + csA[8 + wh * 2 + 1][l16] + csA[12 + wh * 2 + 1][l16]);
        #pragma unroll
        for (int cb = 0; cb < 4; ++cb) {
            #pragma unroll
            for (int r2 = 0; r2 < 4; ++r2) {
                const int c = cb * 16 + quad * 4 + r2;
                const int moff0 = c * 64 + wh * 32 + l16;
                float v0 = acc0[cb][r2] + Sc[moff0] + Sc[4096 + moff0] + Sc[8192 + moff0];
                float v1 = acc1[cb][r2] + Sc[moff0 + 16] + Sc[4096 + moff0 + 16] + Sc[8192 + moff0 + 16];
                const size_t idx0 = ((size_t)(b * 64 + c)) * L_ + m0 + wh * 32 + l16;
                out[idx0]      = fmaf(rinv0, v0, x[idx0]);
                out[idx0 + 16] = fmaf(rinv1, v1, x[idx0 + 16]);
            }
        }
    }
}

extern "C" void kernel_launch(void* const* d_in, const int* in_sizes, int n_in,
                              void* d_out, int out_size, void* d_ws, size_t ws_size,
                              hipStream_t stream) {
    const float* x  = (const float*)d_in[0];
    const float* Wq = (const float*)d_in[1];
    const float* bq = (const float*)d_in[2];
    const float* Wk = (const float*)d_in[3];
    const float* bk = (const float*)d_in[4];
    const float* Wv = (const float*)d_in[5];
    const float* bv = (const float*)d_in[6];
    const float* gm = (const float*)d_in[7];
    float* out = (float*)d_out;

    __bf16* ws    = (__bf16*)d_ws;
    __bf16* qo    = ws;                         // 262144 bf16
    __bf16* ko    = ws + 262144;                // 262144 bf16
    __bf16* vpack = ws + 524288;                // 2097152 bf16

    qkv_kernel<<<dim3(B_ * (L_ / 64)), dim3(256), 0, stream>>>(
        x, Wq, bq, Wk, bk, Wv, bv, qo, ko, vpack);
    attn_kernel<<<dim3(B_ * 64), dim3(512), 0, stream>>>(
        qo, ko, vpack, x, gm, out);
}